// Round 1
// 577.054 us; speedup vs baseline: 1.1359x; 1.1359x over previous
//
#include <hip/hip_runtime.h>
#include <stdint.h>

#define AS1 __attribute__((address_space(1)))
#define AS3 __attribute__((address_space(3)))

typedef unsigned short US;
typedef __bf16 bf16x8 __attribute__((ext_vector_type(8)));
typedef float f32x4 __attribute__((ext_vector_type(4)));

static constexpr int Bsz = 16384;
static constexpr int DIN = 512;
static constexpr int DH  = 1024;
static constexpr int LDA = 2560;   // Ab row: [h(1024) | x(512) | s(1024)]
static constexpr int LDR = 1536;   // RH row: [r*h(1024) | x(512)]; htilde overwrites cols 0:1024

__device__ __forceinline__ US f2bf(float f) {
  unsigned u = __float_as_uint(f);
  u += 0x7fffu + ((u >> 16) & 1u);          // RNE
  return (US)(u >> 16);
}
__device__ __forceinline__ float bf2f(US u) { return __uint_as_float(((unsigned)u) << 16); }
__device__ __forceinline__ float sigm(float x) { return 1.f / (1.f + __expf(-x)); }
__device__ __forceinline__ float tanh_f(float x) { return 1.f - 2.f / (1.f + __expf(2.f * x)); }

// ---------- convert kernels ----------
// Ab[:,0:1024]=bf16(h), Ab[:,1024:1536]=bf16(x); RH[:,1024:1536]=bf16(x)
__global__ void pack_A(const float* __restrict__ h, const float* __restrict__ x,
                       US* __restrict__ Ab, US* __restrict__ RHx) {
  const int total = Bsz * 384;              // 1536 cols / 4 per item
  for (int idx = blockIdx.x * blockDim.x + threadIdx.x; idx < total;
       idx += gridDim.x * blockDim.x) {
    int row = idx / 384;
    int c = (idx - row * 384) * 4;
    const float* src = (c < DH) ? (h + (size_t)row * DH + c)
                                : (x + (size_t)row * DIN + (c - DH));
    float4 v = *(const float4*)src;
    ushort4 o;
    o.x = f2bf(v.x); o.y = f2bf(v.y); o.z = f2bf(v.z); o.w = f2bf(v.w);
    *(ushort4*)(Ab + (size_t)row * LDA + c) = o;
    if (c >= DH) *(ushort4*)(RHx + (size_t)row * LDR + c) = o;
  }
}

// copies [1024 x kseg] f32 row-major into bf16 panel at column offset co, row stride ld
struct WSlot { const float* src; US* dst; int n4; int ksh; int ld; int co; };
struct WBatch { WSlot s[11]; };
__global__ void conv_w(WBatch b) {
  WSlot sl = b.s[blockIdx.y];   // uniform per block
  const int mask = (1 << sl.ksh) - 1;
  for (int i = blockIdx.x * blockDim.x + threadIdx.x; i < sl.n4;
       i += gridDim.x * blockDim.x) {
    float4 v = *(const float4*)(sl.src + (size_t)i * 4);
    ushort4 o;
    o.x = f2bf(v.x); o.y = f2bf(v.y); o.z = f2bf(v.z); o.w = f2bf(v.w);
    int r = i >> sl.ksh;
    int cc = (i & mask) * 4;
    *(ushort4*)(sl.dst + (size_t)r * sl.ld + sl.co + cc) = o;
  }
}

// ---------- 256x256 8-phase GEMM, C = A @ W^T, fused epilogue ----------
// 8 waves (2M x 4N), BK=64, double-buffered 128KiB LDS, counted vmcnt(4) at
// K-tile boundaries only (never drained mid-loop), raw s_barrier phases,
// setprio(1) around MFMA clusters, XOR-swizzled LDS (verified conflict-free).
//
// Stage schedule (tile t occupies buf[t&1]; all 4 half-tiles of a tile are
// guaranteed resident by the boundary vmcnt(4)+barrier that precedes it):
//   t.p0: A-half0(t+1)->buf^1   t.p1: A-half1(t+1)->buf^1
//   t.p2: B-half0(t+2)->buf     t.p3: B-half1(t+2)->buf
// Legality: A-halves of buf^1 last read at (t-1).p2; B-halves of buf last
// read at t.p1 (both protected by the intervening end-of-phase barrier).
// Boundary accounting (steady state): 12 loads outstanding, oldest 8 = the
// 4 half-tiles of tile t+1 -> vmcnt(4); leaves B(t+2) (4 loads) in flight.
//
// EPI: 0=s(tanh,+delta*Wst -> Ab cols 1536:2560)  1=r(sigm*h_prev -> RH)
//      2=z(sigm -> Zb)  3=htilde(tanh -> RH cols 0:1024, row-slab-safe alias)
//      4=T(sigm; h_t=(1-z)(T*h)+z*ht -> f32 out)
template <int EPI>
__global__ __launch_bounds__(512, 2) void gemm8(
    const US* __restrict__ A, int lda,
    const US* __restrict__ W, int ldw, int nt,
    const float* __restrict__ bias,
    const void* aux0, const void* aux1, const void* aux2,
    void* outp, int ldo) {
  __shared__ __align__(16) US As[2][256 * 64];
  __shared__ __align__(16) US Bs[2][256 * 64];

  const int tid  = threadIdx.x;
  const int lane = tid & 63;
  const int w    = tid >> 6;          // wave 0..7
  const int wr   = w >> 2;            // 0..1 : m half (128 rows)
  const int wc   = w & 3;             // 0..3 : n quarter (64 cols)
  const int quad = lane >> 4, l15 = lane & 15;
  const int sw8  = l15 & 7;
  const int lrow = lane >> 3;         // staging: row within 8-row slice
  const int scc  = (lane & 7) ^ (lrow & 7);   // pre-swizzled source chunk

  // XCD swizzle: 256 blocks = 1/CU. XCD c gets m-blocks [c*8, c*8+8) x all
  // 4 n-peers -> each A K-tile fetched once per XCD L2, shared by 4 blocks.
  const int p = blockIdx.x;
  const int c = p & 7, q = p >> 3;
  const int nIdx = q & 3, mIdx = c * 8 + (q >> 2);
  const int mBase = mIdx * 256, nBase = nIdx * 256;

  f32x4 acc[8][4];
#pragma unroll
  for (int i = 0; i < 8; i++)
#pragma unroll
    for (int j = 0; j < 4; j++) acc[i][j] = f32x4{0.f, 0.f, 0.f, 0.f};

  // LDS(row, cc) = G(row, cc ^ (row&7)): linear dest for global_load_lds,
  // inverse-swizzled per-lane source, swizzle reapplied on ds_read.
#define STAGE_A(d, hh, tt)                                                       \
  { const US* g = A + (size_t)(mBase + (hh)*128 + w * 8 + lrow) * lda +          \
                  (tt) * 64 + scc * 8;                                           \
    __builtin_amdgcn_global_load_lds((AS1 const void*)g,                         \
        (AS3 void*)&As[d][((hh)*128 + w * 8) * 64], 16, 0, 0);                   \
    __builtin_amdgcn_global_load_lds((AS1 const void*)(g + (size_t)64 * lda),    \
        (AS3 void*)&As[d][((hh)*128 + 64 + w * 8) * 64], 16, 0, 0); }
#define STAGE_B(d, hh, tt)                                                       \
  { const US* g = W + (size_t)(nBase + (hh)*128 + w * 8 + lrow) * ldw +          \
                  (tt) * 64 + scc * 8;                                           \
    __builtin_amdgcn_global_load_lds((AS1 const void*)g,                         \
        (AS3 void*)&Bs[d][((hh)*128 + w * 8) * 64], 16, 0, 0);                   \
    __builtin_amdgcn_global_load_lds((AS1 const void*)(g + (size_t)64 * ldw),    \
        (AS3 void*)&Bs[d][((hh)*128 + 64 + w * 8) * 64], 16, 0, 0); }

#define READ_A(mh)                                                               \
  _Pragma("unroll")                                                              \
  for (int i = 0; i < 4; ++i)                                                    \
    _Pragma("unroll")                                                            \
    for (int ks = 0; ks < 2; ++ks)                                               \
      af[i][ks] = *(const bf16x8*)&As[cur][(wr * 128 + (mh)*64 + i * 16 + l15)   \
                                          * 64 + (((ks * 4 + quad) ^ sw8) * 8)];
#define READ_B(BSET, nh)                                                         \
  _Pragma("unroll")                                                              \
  for (int j = 0; j < 2; ++j)                                                    \
    _Pragma("unroll")                                                            \
    for (int ks = 0; ks < 2; ++ks)                                               \
      BSET[j][ks] = *(const bf16x8*)&Bs[cur][(wc * 64 + (nh)*32 + j * 16 + l15)  \
                                            * 64 + (((ks * 4 + quad) ^ sw8) * 8)];
#define MFMA_Q(mh, BSET, nh)                                                     \
  _Pragma("unroll")                                                              \
  for (int ks = 0; ks < 2; ++ks)                                                 \
    _Pragma("unroll")                                                            \
    for (int i = 0; i < 4; ++i)                                                  \
      _Pragma("unroll")                                                          \
      for (int j = 0; j < 2; ++j)                                                \
        acc[(mh)*4 + i][(nh)*2 + j] = __builtin_amdgcn_mfma_f32_16x16x32_bf16(   \
            af[i][ks], BSET[j][ks], acc[(mh)*4 + i][(nh)*2 + j], 0, 0, 0);

  // ---- prologue: tile0 fully + B halves of tile1; retire tile0 only ----
  STAGE_A(0, 0, 0); STAGE_A(0, 1, 0); STAGE_B(0, 0, 0); STAGE_B(0, 1, 0);
  if (nt > 1) { STAGE_B(1, 0, 1); STAGE_B(1, 1, 1); }
  if (nt > 1) __builtin_amdgcn_s_waitcnt(0x0f74);   // vmcnt(4)
  else        __builtin_amdgcn_s_waitcnt(0x0f70);   // vmcnt(0)
  __builtin_amdgcn_s_barrier();
  __builtin_amdgcn_sched_barrier(0);

  bf16x8 af[4][2], b0[2][2], b1[2][2];
  int cur = 0;

  for (int t = 0; t < nt; ++t, cur ^= 1) {
    const int nxt = cur ^ 1;
    // ---- phase 0: Q(m0,n0); prefetch A-half0(t+1) ----
    READ_A(0);
    READ_B(b0, 0);
    if (t + 1 < nt) STAGE_A(nxt, 0, t + 1);
    __builtin_amdgcn_s_barrier();
    __builtin_amdgcn_s_setprio(1);
    MFMA_Q(0, b0, 0);
    __builtin_amdgcn_s_setprio(0);
    __builtin_amdgcn_s_barrier();
    // ---- phase 1: Q(m0,n1); prefetch A-half1(t+1) ----
    READ_B(b1, 1);
    if (t + 1 < nt) STAGE_A(nxt, 1, t + 1);
    __builtin_amdgcn_s_barrier();
    __builtin_amdgcn_s_setprio(1);
    MFMA_Q(0, b1, 1);
    __builtin_amdgcn_s_setprio(0);
    __builtin_amdgcn_s_barrier();
    // ---- phase 2: Q(m1,n0); prefetch B-half0(t+2) into buf[cur] ----
    READ_A(1);
    if (t + 2 < nt) STAGE_B(cur, 0, t + 2);
    __builtin_amdgcn_s_barrier();
    __builtin_amdgcn_s_setprio(1);
    MFMA_Q(1, b0, 0);
    __builtin_amdgcn_s_setprio(0);
    __builtin_amdgcn_s_barrier();
    // ---- phase 3: Q(m1,n1); prefetch B-half1(t+2); K-tile boundary ----
    if (t + 2 < nt) STAGE_B(cur, 1, t + 2);
    __builtin_amdgcn_s_barrier();
    __builtin_amdgcn_s_setprio(1);
    MFMA_Q(1, b1, 1);
    __builtin_amdgcn_s_setprio(0);
    if (t + 1 < nt) {
      if (t + 2 < nt) __builtin_amdgcn_s_waitcnt(0x0f74);  // vmcnt(4)
      else            __builtin_amdgcn_s_waitcnt(0x0f70);  // vmcnt(0) drain
      __builtin_amdgcn_s_barrier();
      __builtin_amdgcn_sched_barrier(0);   // pin next tile's ds_reads here
    }
  }
#undef STAGE_A
#undef STAGE_B
#undef READ_A
#undef READ_B
#undef MFMA_Q

  // epilogue: row = mBase+wr*128+im*16+quad*4+r ; col = nBase+wc*64+jn*16+l15
#pragma unroll
  for (int im = 0; im < 8; ++im) {
#pragma unroll
    for (int jn = 0; jn < 4; ++jn) {
      const int col = nBase + wc * 64 + jn * 16 + l15;
      const float bv = bias[col];
#pragma unroll
      for (int r = 0; r < 4; ++r) {
        const int row = mBase + wr * 128 + im * 16 + quad * 4 + r;
        float v = acc[im][jn][r] + bv;
        if constexpr (EPI == 0) {
          const float* delta = (const float*)aux0;
          const float* wst   = (const float*)aux1;
          v += delta[row] * wst[col];
          ((US*)outp)[(size_t)row * ldo + col] = f2bf(tanh_f(v));
        } else if constexpr (EPI == 1) {
          const float* hp = (const float*)aux0;   // pristine f32 h_prev
          float rr = sigm(v);
          ((US*)outp)[(size_t)row * ldo + col] =
              f2bf(rr * hp[(size_t)row * DH + col]);
        } else if constexpr (EPI == 2) {
          ((US*)outp)[(size_t)row * ldo + col] = f2bf(sigm(v));
        } else if constexpr (EPI == 3) {
          ((US*)outp)[(size_t)row * ldo + col] = f2bf(tanh_f(v));
        } else {
          const float* hp = (const float*)aux0;   // pristine f32 h_prev
          const US* Zp = (const US*)aux1;         // stride DH
          const US* Hp = (const US*)aux2;         // htilde in RH, stride LDR
          float T = sigm(v);
          size_t o = (size_t)row * DH + col;
          float z = bf2f(Zp[o]), ht = bf2f(Hp[(size_t)row * LDR + col]);
          float h = hp[o];
          ((float*)outp)[(size_t)row * ldo + col] = (1.f - z) * (T * h) + z * ht;
        }
      }
    }
  }
}

extern "C" void kernel_launch(void* const* d_in, const int* in_sizes, int n_in,
                              void* d_out, int out_size, void* d_ws, size_t ws_size,
                              hipStream_t stream) {
  const float* x_t   = (const float*)d_in[0];
  const float* delta = (const float*)d_in[1];
  const float* h_prev= (const float*)d_in[2];
  const float* W_sh  = (const float*)d_in[3];
  const float* W_sx  = (const float*)d_in[4];
  const float* W_st  = (const float*)d_in[5];
  const float* b_s   = (const float*)d_in[6];
  const float* WTh   = (const float*)d_in[7];
  const float* WTx   = (const float*)d_in[8];
  const float* WTs   = (const float*)d_in[9];
  const float* b_T   = (const float*)d_in[10];
  const float* W_rh  = (const float*)d_in[11];
  const float* W_rx  = (const float*)d_in[12];
  const float* b_r   = (const float*)d_in[13];
  const float* W_zh  = (const float*)d_in[14];
  const float* W_zx  = (const float*)d_in[15];
  const float* b_z   = (const float*)d_in[16];
  const float* W_h   = (const float*)d_in[17];
  const float* W_x   = (const float*)d_in[18];
  const float* b_    = (const float*)d_in[19];
  float* out = (float*)d_out;

  char* ws = (char*)d_ws;
  US* Ab = (US*)ws;                         size_t off = (size_t)Bsz * LDA * 2;   // 80MB
  US* RH = (US*)(ws + off);                 off += (size_t)Bsz * LDR * 2;         // 48MB
  US* Zb = (US*)(ws + off);                 off += (size_t)Bsz * DH * 2;          // 32MB
  // K-concatenated bf16 weight panels: [out=1024 x K]
  US* bWs = (US*)(ws + off); off += (size_t)DH * 1536 * 2;   // [W_sh | W_sx]
  US* bWr = (US*)(ws + off); off += (size_t)DH * 1536 * 2;   // [W_rh | W_rx]
  US* bWz = (US*)(ws + off); off += (size_t)DH * 1536 * 2;   // [W_zh | W_zx]
  US* bWT = (US*)(ws + off); off += (size_t)DH * 2560 * 2;   // [WTh | WTx | WTs]
  US* bWh = (US*)(ws + off); off += (size_t)DH * 1536 * 2;   // [W_h  | W_x ]

  // Stage 0: convert
  pack_A<<<dim3(8192), 256, 0, stream>>>(h_prev, x_t, Ab, RH);
  WBatch wb;
  const int n4h = DH * DH / 4, n4x = DH * DIN / 4;   // ksh: 1024->8, 512->7
  wb.s[0]  = {W_sh, bWs, n4h, 8, 1536, 0};
  wb.s[1]  = {W_sx, bWs, n4x, 7, 1536, 1024};
  wb.s[2]  = {W_rh, bWr, n4h, 8, 1536, 0};
  wb.s[3]  = {W_rx, bWr, n4x, 7, 1536, 1024};
  wb.s[4]  = {W_zh, bWz, n4h, 8, 1536, 0};
  wb.s[5]  = {W_zx, bWz, n4x, 7, 1536, 1024};
  wb.s[6]  = {WTh,  bWT, n4h, 8, 2560, 0};
  wb.s[7]  = {WTx,  bWT, n4x, 7, 2560, 1024};
  wb.s[8]  = {WTs,  bWT, n4h, 8, 2560, 1536};
  wb.s[9]  = {W_h,  bWh, n4h, 8, 1536, 0};
  wb.s[10] = {W_x,  bWh, n4x, 7, 1536, 1024};
  conv_w<<<dim3(512, 11), 256, 0, stream>>>(wb);

  const dim3 grid(256);   // (DH/256) * (Bsz/256) = 4 * 64 ; 1 block/CU

  // Phase 1: s -> Ab cols 1536:2560 (reads cols 0:1536 only; col-disjoint)
  gemm8<0><<<grid, 512, 0, stream>>>(Ab, LDA, bWs, 1536, 24, b_s,
                                     delta, W_st, nullptr, (void*)(Ab + 1536), LDA);
  // r*h -> RH cols 0:1024
  gemm8<1><<<grid, 512, 0, stream>>>(Ab, LDA, bWr, 1536, 24, b_r,
                                     h_prev, nullptr, nullptr, (void*)RH, LDR);
  // z -> Zb
  gemm8<2><<<grid, 512, 0, stream>>>(Ab, LDA, bWz, 1536, 24, b_z,
                                     nullptr, nullptr, nullptr, (void*)Zb, DH);
  // Phase 2: htilde = tanh([r*h|x] @ [W_h|W_x]^T + b) -> RH cols 0:1024
  // (row-slab-safe in-place: each block reads only its own 256-row slab,
  //  all staging drained before its epilogue writes)
  gemm8<3><<<grid, 512, 0, stream>>>(RH, LDR, bWh, 1536, 24, b_,
                                     nullptr, nullptr, nullptr, (void*)RH, LDR);
  // Phase 3: T gate ([h|x|s] K=2560) + final combine -> d_out (f32)
  gemm8<4><<<grid, 512, 0, stream>>>(Ab, LDA, bWT, 2560, 40, b_T,
                                     h_prev, Zb, RH, (void*)out, DH);
}